// Round 4
// baseline (123.161 us; speedup 1.0000x reference)
//
#include <hip/hip_runtime.h>
#include <hip/hip_bf16.h>
#include <math.h>

#define DM 64
#define NH 4
#define HD 16
#define BATCH 16
#define TSEQ 1024
#define VROWS 32   // vt padded d-rows: 0-15 data, 16 = ones, 17-31 garbage (never read into live output)

typedef short bf16x8 __attribute__((ext_vector_type(8)));
typedef short bf16x4 __attribute__((ext_vector_type(4)));
typedef float f32x4  __attribute__((ext_vector_type(4)));
typedef float f32x16 __attribute__((ext_vector_type(16)));

static __device__ inline short f2bf(float x) {
    __hip_bfloat16 h = __float2bfloat16(x);
    return __builtin_bit_cast(short, h);
}
static __device__ inline float bf2f(short s) {
    __hip_bfloat16 h = __builtin_bit_cast(__hip_bfloat16, s);
    return __bfloat162float(h);
}

// ---------------- Kernel 1: fused Q/K/V projections -> bf16 (hi/lo) --------
// grid = (32 rowblocks of 512 rows, 24 parts), 256 thr; thread = 2 rows x 8
// cols. parts 0-7: q (scaled 0.25*log2e, hi/lo), 8-15: k (hi/lo), 16-23: v ->
// transposed vt[d][key] + ones-row d=16. W slice in LDS; 2-row blocking
// halves ds_read cost per FMA; x loads issued before the staging barrier.
__global__ __launch_bounds__(256) void proj_kernel(
    const float* __restrict__ x, const float* __restrict__ enc,
    const float* __restrict__ Wkv, const float* __restrict__ bkv,
    const float* __restrict__ Wq,  const float* __restrict__ bq,
    short* __restrict__ qhi, short* __restrict__ qlo,
    short* __restrict__ khi, short* __restrict__ klo,
    short* __restrict__ vt)
{
    const int t = threadIdx.x;
    const int part = blockIdx.y;           // 0..23
    const int r0 = blockIdx.x * 512 + t;   // this thread: rows r0, r0+256

    const float* in; const float* W; const float* bias; int cb, ldw;
    if (part < 8)       { in = x;   W = Wq;  ldw = 64;  cb = part*8;           bias = bq;  }
    else if (part < 16) { in = enc; W = Wkv; ldw = 128; cb = (part-8)*8;       bias = bkv; }
    else                { in = enc; W = Wkv; ldw = 128; cb = 64 + (part-16)*8; bias = bkv; }

    const float4* row0 = (const float4*)(in + (size_t)r0*64);
    const float4* row1 = (const float4*)(in + (size_t)(r0+256)*64);

    // issue first x chunk before LDS staging so latency overlaps the barrier
    float4 xc[2][4];
    #pragma unroll
    for (int v4 = 0; v4 < 4; ++v4) { xc[0][v4] = row0[v4]; xc[1][v4] = row1[v4]; }

    __shared__ float wsl[64][8];
    wsl[t >> 3][t & 7] = W[(t >> 3)*ldw + cb + (t & 7)];
    {
        int i1 = t + 256;
        wsl[i1 >> 3][i1 & 7] = W[(i1 >> 3)*ldw + cb + (i1 & 7)];
    }
    __syncthreads();

    float acc[2][8];
    #pragma unroll
    for (int j = 0; j < 8; ++j) { float bj = bias[cb + j]; acc[0][j] = bj; acc[1][j] = bj; }

    for (int kc = 0; kc < 4; ++kc) {
        float4 xn[2][4];
        if (kc < 3) {
            #pragma unroll
            for (int v4 = 0; v4 < 4; ++v4) {
                xn[0][v4] = row0[(kc+1)*4 + v4];
                xn[1][v4] = row1[(kc+1)*4 + v4];
            }
        }
        #pragma unroll
        for (int i = 0; i < 16; ++i) {
            const int k = kc*16 + i;
            const float4 w0 = ((const float4*)&wsl[k][0])[0];
            const float4 w1 = ((const float4*)&wsl[k][0])[1];
            const float xv0 = ((const float*)&xc[0][i >> 2])[i & 3];
            const float xv1 = ((const float*)&xc[1][i >> 2])[i & 3];
            acc[0][0] += xv0*w0.x; acc[0][1] += xv0*w0.y; acc[0][2] += xv0*w0.z; acc[0][3] += xv0*w0.w;
            acc[0][4] += xv0*w1.x; acc[0][5] += xv0*w1.y; acc[0][6] += xv0*w1.z; acc[0][7] += xv0*w1.w;
            acc[1][0] += xv1*w0.x; acc[1][1] += xv1*w0.y; acc[1][2] += xv1*w0.z; acc[1][3] += xv1*w0.w;
            acc[1][4] += xv1*w1.x; acc[1][5] += xv1*w1.y; acc[1][6] += xv1*w1.z; acc[1][7] += xv1*w1.w;
        }
        if (kc < 3) {
            #pragma unroll
            for (int v4 = 0; v4 < 4; ++v4) { xc[0][v4] = xn[0][v4]; xc[1][v4] = xn[1][v4]; }
        }
    }

    if (part < 16) {
        const float scale = (part < 8) ? 0.36067376022224085f : 1.0f;  // 0.25*log2(e) for q
        short* dh = (part < 8) ? qhi : khi;
        short* dl = (part < 8) ? qlo : klo;
        const int h  = cb >> 4;       // head
        const int d0 = cb & 15;       // 0 or 8
        #pragma unroll
        for (int rr = 0; rr < 2; ++rr) {
            const int r = r0 + rr*256;
            const int b = r >> 10, trow = r & 1023;
            bf16x8 hv, lv;
            #pragma unroll
            for (int j = 0; j < 8; ++j) {
                float vf = acc[rr][j] * scale;
                short hb = f2bf(vf);
                hv[j] = hb;
                lv[j] = f2bf(vf - bf2f(hb));
            }
            size_t off = (((size_t)(b*NH + h))*TSEQ + trow)*HD + d0;
            *(bf16x8*)(dh + off) = hv;
            *(bf16x8*)(dl + off) = lv;
        }
    } else {
        const int h  = (part - 16) >> 1;
        const int d0 = ((part - 16) & 1) * 8;
        #pragma unroll
        for (int rr = 0; rr < 2; ++rr) {
            const int r = r0 + rr*256;
            const int b = r >> 10, trow = r & 1023;
            short* base = vt + ((size_t)(b*NH + h))*VROWS*TSEQ;
            #pragma unroll
            for (int j = 0; j < 8; ++j)
                base[(size_t)(d0 + j)*TSEQ + trow] = f2bf(acc[rr][j]);
            if (d0 == 8) base[(size_t)16*TSEQ + trow] = (short)0x3F80;  // ones row for l-trick
        }
    }
}

// ---------------- Kernel 2: MFMA flash attention + Wproj epilogue ----------
// grid = (32 q-tiles of 32 rows, 16 batches), 512 thr = 8 waves =
// (4 heads x 2 key-halves). Per 32-key step:
//   S[32q,32k] = 3x mfma_32x32x16_bf16 (q/k hi-lo)
//   p = exp2(S)*maskbit (no-max softmax; 0.25*log2e pre-folded into q)
//   P -> per-wave LDS as bf16 (stride 36 shorts; b64 reads 2-way-free)
//   ctx += 2x mfma_32x32x16_bf16 vs V-transposed; V col 16 = ones so
//   C[q][16] accumulates l for free (no lacc regs / no shuffle reduce).
// K/V/mask frags for step+1 prefetched. Partials combine in LDS; epilogue
// normalizes and applies Wproj.
__global__ __launch_bounds__(512) void attn_kernel(
    const short* __restrict__ qhi, const short* __restrict__ qlo,
    const short* __restrict__ khi, const short* __restrict__ klo,
    const short* __restrict__ vt,  const int* __restrict__ mask,
    const float* __restrict__ Wproj, const float* __restrict__ bproj,
    float* __restrict__ out)
{
    const int tid  = threadIdx.x;
    const int lane = tid & 63;
    const int wid  = __builtin_amdgcn_readfirstlane(tid >> 6);  // 0..7
    const int h  = wid & 3;
    const int ks = wid >> 2;
    const int qbase = blockIdx.x * 32;
    const int b  = blockIdx.y;
    const int l31 = lane & 31, half = lane >> 5;

    __shared__ short Pb[8][32][36];      // [wave][q-row][key(+pad)] bf16
    __shared__ float Cbuf[2][32][68];
    __shared__ float Lbuf[2][NH][32];

    // Q A-frags: A[m=l31][k=half*8+j]
    const size_t qoff = (((size_t)(b*NH + h))*TSEQ + qbase + l31)*HD + half*8;
    const bf16x8 qAh = *(const bf16x8*)(qhi + qoff);
    const bf16x8 qAl = *(const bf16x8*)(qlo + qoff);

    const short* khb  = khi + (((size_t)(b*NH + h))*TSEQ + ks*512)*HD;
    const short* klb  = klo + (((size_t)(b*NH + h))*TSEQ + ks*512)*HD;
    const short* vtb  = vt  + ((size_t)(b*NH + h))*VROWS*TSEQ + ks*512;
    const int*   mrow = mask + b*TSEQ + ks*512;

    f32x16 Cacc;
    #pragma unroll
    for (int i = 0; i < 16; ++i) Cacc[i] = 0.f;

    short* prow_w = &Pb[wid][0][0];
    const short* prA = &Pb[wid][l31][0];

    // prefetched step-0 frags
    bf16x8 kBh = *(const bf16x8*)(khb + (size_t)l31*HD + half*8);
    bf16x8 kBl = *(const bf16x8*)(klb + (size_t)l31*HD + half*8);
    bf16x8 vB0 = *(const bf16x8*)(vtb + (size_t)l31*TSEQ + half*8);
    bf16x8 vB1 = *(const bf16x8*)(vtb + (size_t)l31*TSEQ + 16 + half*8);
    int mk = mrow[l31];

    for (int step = 0; step < 16; ++step) {
        // prefetch next step's frags (redundant reload of step 15: harmless)
        const int nko = ((step < 15) ? step + 1 : 15) * 32;
        const bf16x8 nkBh = *(const bf16x8*)(khb + (size_t)(nko + l31)*HD + half*8);
        const bf16x8 nkBl = *(const bf16x8*)(klb + (size_t)(nko + l31)*HD + half*8);
        const bf16x8 nvB0 = *(const bf16x8*)(vtb + (size_t)l31*TSEQ + nko + half*8);
        const bf16x8 nvB1 = *(const bf16x8*)(vtb + (size_t)l31*TSEQ + nko + 16 + half*8);
        const int    nmk  = mrow[nko + l31];

        f32x16 S;
        #pragma unroll
        for (int i = 0; i < 16; ++i) S[i] = 0.f;
        S = __builtin_amdgcn_mfma_f32_32x32x16_bf16(qAh, kBh, S, 0, 0, 0);
        S = __builtin_amdgcn_mfma_f32_32x32x16_bf16(qAh, kBl, S, 0, 0, 0);
        S = __builtin_amdgcn_mfma_f32_32x32x16_bf16(qAl, kBh, S, 0, 0, 0);

        #pragma unroll
        for (int i = 0; i < 16; ++i) {
            float p = __builtin_amdgcn_exp2f(S[i]);
            p = (mk != 0) ? p : 0.0f;
            const int row = (i & 3) + 8*(i >> 2) + 4*half;   // 32x32 C/D row
            prow_w[row*36 + l31] = f2bf(p);
        }
        // same-wave LDS write->read: compiler orders via lgkmcnt, no barrier

        // P A-frags: A[m=l31][k]; keys kc*16 + half*8 + j  (2x b64, 8B-aligned)
        const bf16x4 a0 = *(const bf16x4*)(prA + half*8);
        const bf16x4 a1 = *(const bf16x4*)(prA + half*8 + 4);
        const bf16x4 a2 = *(const bf16x4*)(prA + 16 + half*8);
        const bf16x4 a3 = *(const bf16x4*)(prA + 16 + half*8 + 4);
        const bf16x8 pA0 = __builtin_shufflevector(a0, a1, 0, 1, 2, 3, 4, 5, 6, 7);
        const bf16x8 pA1 = __builtin_shufflevector(a2, a3, 0, 1, 2, 3, 4, 5, 6, 7);

        Cacc = __builtin_amdgcn_mfma_f32_32x32x16_bf16(pA0, vB0, Cacc, 0, 0, 0);
        Cacc = __builtin_amdgcn_mfma_f32_32x32x16_bf16(pA1, vB1, Cacc, 0, 0, 0);

        kBh = nkBh; kBl = nkBl; vB0 = nvB0; vB1 = nvB1; mk = nmk;
    }

    // publish partials: cols 0-15 = ctx(d), col 16 = l
    #pragma unroll
    for (int r = 0; r < 16; ++r) {
        const int row = (r & 3) + 8*(r >> 2) + 4*half;
        if (l31 < 16)        Cbuf[ks][row][h*HD + l31] = Cacc[r];
        else if (l31 == 16)  Lbuf[ks][h][row] = Cacc[r];
    }
    __syncthreads();

    // epilogue: thread = (q=tid>>4, 4 out cols); combine key-halves,
    // normalize per head, apply Wproj + bproj
    const int q   = tid >> 4;        // 0..31
    const int cbo = (tid & 15) * 4;  // 0..60
    float linv[NH];
    #pragma unroll
    for (int hh = 0; hh < NH; ++hh)
        linv[hh] = 1.0f / (Lbuf[0][hh][q] + Lbuf[1][hh][q]);

    float o0 = bproj[cbo], o1 = bproj[cbo+1], o2 = bproj[cbo+2], o3 = bproj[cbo+3];
    #pragma unroll
    for (int i = 0; i < 64; ++i) {
        float cv = (Cbuf[0][q][i] + Cbuf[1][q][i]) * linv[i >> 4];
        const float4 wr = *(const float4*)(Wproj + i*DM + cbo);
        o0 += cv*wr.x; o1 += cv*wr.y; o2 += cv*wr.z; o3 += cv*wr.w;
    }
    float4 st; st.x = o0; st.y = o1; st.z = o2; st.w = o3;
    *(float4*)(out + ((size_t)b*TSEQ + qbase + q)*DM + cbo) = st;
}

extern "C" void kernel_launch(void* const* d_in, const int* in_sizes, int n_in,
                              void* d_out, int out_size, void* d_ws, size_t ws_size,
                              hipStream_t stream) {
    const float* x     = (const float*)d_in[0];
    const float* enc   = (const float*)d_in[1];
    const int*   mask  = (const int*)  d_in[2];
    const float* Wkv   = (const float*)d_in[3];
    const float* bkv   = (const float*)d_in[4];
    const float* Wq    = (const float*)d_in[5];
    const float* bq    = (const float*)d_in[6];
    const float* Wproj = (const float*)d_in[7];
    const float* bproj = (const float*)d_in[8];
    float* out = (float*)d_out;

    // ws: qhi,qlo,khi,klo 2MB each + vt (32 padded d-rows) 4MB = 12MB
    const size_t SZ = (size_t)BATCH*NH*TSEQ*HD;
    short* qhi = (short*)d_ws;
    short* qlo = qhi + SZ;
    short* khi = qlo + SZ;
    short* klo = khi + SZ;
    short* vt  = klo + SZ;   // BATCH*NH*VROWS*TSEQ shorts

    proj_kernel<<<dim3(32, 24), dim3(256), 0, stream>>>(
        x, enc, Wkv, bkv, Wq, bq, qhi, qlo, khi, klo, vt);
    attn_kernel<<<dim3(32, 16), dim3(512), 0, stream>>>(
        qhi, qlo, khi, klo, vt, mask, Wproj, bproj, out);
}

// Round 5
// 112.889 us; speedup vs baseline: 1.0910x; 1.0910x over previous
//
#include <hip/hip_runtime.h>
#include <hip/hip_bf16.h>
#include <math.h>

#define DM 64
#define NH 4
#define HD 16
#define BATCH 16
#define TSEQ 1024

typedef short bf16x8 __attribute__((ext_vector_type(8)));
typedef short bf16x4 __attribute__((ext_vector_type(4)));
typedef float f32x4  __attribute__((ext_vector_type(4)));
typedef float f32x16 __attribute__((ext_vector_type(16)));

static __device__ inline short f2bf(float x) {
    __hip_bfloat16 h = __float2bfloat16(x);
    return __builtin_bit_cast(short, h);
}
static __device__ inline float bf2f(short s) {
    __hip_bfloat16 h = __builtin_bit_cast(__hip_bfloat16, s);
    return __bfloat162float(h);
}

// ---------------- Kernel 1: fused Q/K/V projections -> bf16 ---------------
// grid = (64 rowblocks, 12 parts), 256 thr, thread = 1 row x 16 cols (one
// full head). parts 0-3: q (scaled 0.25*log2e, hi/lo), 4-7: k (hi/lo),
// 8-11: v -> TILED vtt[b][h][kb][d][kw] with mask folded in (v *= mask,
// ones-row d=16 = mask). x read 4x, enc 8x (was 8x/16x).
__global__ __launch_bounds__(256) void proj_kernel(
    const float* __restrict__ x, const float* __restrict__ enc,
    const float* __restrict__ Wkv, const float* __restrict__ bkv,
    const float* __restrict__ Wq,  const float* __restrict__ bq,
    const int* __restrict__ mask,
    short* __restrict__ qhi, short* __restrict__ qlo,
    short* __restrict__ khi, short* __restrict__ klo,
    short* __restrict__ vtt)
{
    const int t = threadIdx.x;
    const int part = blockIdx.y;          // 0..11
    const int r = blockIdx.x * 256 + t;   // global row 0..16383
    const int b = r >> 10, trow = r & 1023;

    const float* in; const float* W; const float* bias; int cb, ldw;
    if (part < 4)      { in = x;   W = Wq;  ldw = 64;  cb = part*16;          bias = bq;  }
    else if (part < 8) { in = enc; W = Wkv; ldw = 128; cb = (part-4)*16;      bias = bkv; }
    else               { in = enc; W = Wkv; ldw = 128; cb = 64 + (part-8)*16; bias = bkv; }

    __shared__ float wsl[64][16];
    for (int idx = t; idx < 1024; idx += 256)
        wsl[idx >> 4][idx & 15] = W[(idx >> 4)*ldw + cb + (idx & 15)];

    // full input row up front (latency overlaps the staging barrier)
    float4 xr[16];
    const float4* inrow = (const float4*)(in + (size_t)r * 64);
    #pragma unroll
    for (int i = 0; i < 16; ++i) xr[i] = inrow[i];
    __syncthreads();

    float acc[16];
    #pragma unroll
    for (int j = 0; j < 16; ++j) acc[j] = bias[cb + j];
    #pragma unroll
    for (int k = 0; k < 64; ++k) {
        const float xv = ((const float*)xr)[k];
        const float4 w0 = ((const float4*)&wsl[k][0])[0];
        const float4 w1 = ((const float4*)&wsl[k][0])[1];
        const float4 w2 = ((const float4*)&wsl[k][0])[2];
        const float4 w3 = ((const float4*)&wsl[k][0])[3];
        acc[0]  += xv*w0.x; acc[1]  += xv*w0.y; acc[2]  += xv*w0.z; acc[3]  += xv*w0.w;
        acc[4]  += xv*w1.x; acc[5]  += xv*w1.y; acc[6]  += xv*w1.z; acc[7]  += xv*w1.w;
        acc[8]  += xv*w2.x; acc[9]  += xv*w2.y; acc[10] += xv*w2.z; acc[11] += xv*w2.w;
        acc[12] += xv*w3.x; acc[13] += xv*w3.y; acc[14] += xv*w3.z; acc[15] += xv*w3.w;
    }

    if (part < 8) {
        // q: fold softmax scale AND log2(e) so attn uses exp2 directly
        const float scale = (part < 4) ? 0.36067376022224085f : 1.0f;
        short* dh = (part < 4) ? qhi : khi;
        short* dl = (part < 4) ? qlo : klo;
        const int h = (part < 4) ? part : (part - 4);
        bf16x8 h0, h1, l0, l1;
        #pragma unroll
        for (int j = 0; j < 16; ++j) {
            float vf = acc[j] * scale;
            short hb = f2bf(vf);
            short lb = f2bf(vf - bf2f(hb));
            if (j < 8) { h0[j] = hb; l0[j] = lb; }
            else       { h1[j-8] = hb; l1[j-8] = lb; }
        }
        size_t off = (((size_t)(b*NH + h))*TSEQ + trow)*HD;
        *(bf16x8*)(dh + off)     = h0;
        *(bf16x8*)(dh + off + 8) = h1;
        *(bf16x8*)(dl + off)     = l0;
        *(bf16x8*)(dl + off + 8) = l1;
    } else {
        // vtt[b][h][kb=key>>5][d(32: 0-15 data, 16 maskbit, 17-31 unused)][kw=key&31]
        const int h = part - 8;
        const float mb = (mask[b*TSEQ + trow] != 0) ? 1.0f : 0.0f;
        short* tile = vtt + ((size_t)(b*NH + h))*32768 + (size_t)(trow >> 5)*1024;
        const int kw = trow & 31;
        #pragma unroll
        for (int j = 0; j < 16; ++j)
            tile[j*32 + kw] = f2bf(acc[j] * mb);
        tile[16*32 + kw] = (mb != 0.0f) ? (short)0x3F80 : (short)0;  // ones/mask row
    }
}

// ---------------- Kernel 2: MFMA flash attention + Wproj epilogue ----------
// grid = (32 q-tiles of 32 rows, 16 batches), 512 thr = 8 waves =
// (4 heads x 2 key-halves). Per 32-key step:
//   S[32q,32k] = 3x mfma_32x32x16_bf16 (q/k hi-lo)
//   p = exp2(S) (no-max softmax; masking pre-folded into V)
//   P -> per-wave LDS bf16 (stride 36 shorts; 8B-aligned b64 frag reads)
//   ctx += 2x mfma_32x32x16_bf16 (A=P, B=tiled vtt -> lane-stride-64B
//   coalesced loads; col 16 of vtt = maskbit so C[q][16] = l for free)
// Partials combine in LDS; epilogue normalizes + applies Wproj.
__global__ __launch_bounds__(512) void attn_kernel(
    const short* __restrict__ qhi, const short* __restrict__ qlo,
    const short* __restrict__ khi, const short* __restrict__ klo,
    const short* __restrict__ vtt,
    const float* __restrict__ Wproj, const float* __restrict__ bproj,
    float* __restrict__ out)
{
    const int tid  = threadIdx.x;
    const int lane = tid & 63;
    const int wid  = __builtin_amdgcn_readfirstlane(tid >> 6);  // 0..7
    const int h  = wid & 3;
    const int ks = wid >> 2;          // key half
    const int qbase = blockIdx.x * 32;
    const int b  = blockIdx.y;
    const int l31 = lane & 31, half = lane >> 5;

    __shared__ short Pb[8][32][36];      // [wave][q-row][key(+pad)] bf16
    __shared__ float Cbuf[2][32][67];    // stride 67: 67*l mod 32 = 3*l -> conflict-free
    __shared__ float Lbuf[2][NH][32];

    // Q A-frags: A[m=l31][k=half*8+j]
    const size_t qoff = (((size_t)(b*NH + h))*TSEQ + qbase + l31)*HD + half*8;
    const bf16x8 qAh = *(const bf16x8*)(qhi + qoff);
    const bf16x8 qAl = *(const bf16x8*)(qlo + qoff);

    const short* khb = khi + (((size_t)(b*NH + h))*TSEQ + ks*512)*HD;
    const short* klb = klo + (((size_t)(b*NH + h))*TSEQ + ks*512)*HD;
    const short* vtb = vtt + ((size_t)(b*NH + h))*32768 + (size_t)ks*16384;

    f32x16 Cacc;
    #pragma unroll
    for (int i = 0; i < 16; ++i) Cacc[i] = 0.f;

    short* pw = &Pb[wid][0][0];
    const short* pr = &Pb[wid][l31][0];

    for (int step = 0; step < 16; ++step) {
        const int ko = step * 32;
        // K B-frags: B[k=half*8+j][n=key=l31]  (1 KB contiguous per wave)
        const bf16x8 kBh = *(const bf16x8*)(khb + (size_t)(ko + l31)*HD + half*8);
        const bf16x8 kBl = *(const bf16x8*)(klb + (size_t)(ko + l31)*HD + half*8);
        // V B-frags from tiled vtt: B[k=kw][n=d=l31]; lane stride 64 B ->
        // the wave consumes the 2 KB tile exactly once, fully coalesced
        const short* tile = vtb + (size_t)step * 1024;
        const bf16x8 vB0 = *(const bf16x8*)(tile + l31*32 + half*8);        // keys 0-15
        const bf16x8 vB1 = *(const bf16x8*)(tile + l31*32 + 16 + half*8);   // keys 16-31

        f32x16 S;
        #pragma unroll
        for (int i = 0; i < 16; ++i) S[i] = 0.f;
        S = __builtin_amdgcn_mfma_f32_32x32x16_bf16(qAh, kBh, S, 0, 0, 0);
        S = __builtin_amdgcn_mfma_f32_32x32x16_bf16(qAh, kBl, S, 0, 0, 0);
        S = __builtin_amdgcn_mfma_f32_32x32x16_bf16(qAl, kBh, S, 0, 0, 0);

        #pragma unroll
        for (int i = 0; i < 16; ++i) {
            const float p = __builtin_amdgcn_exp2f(S[i]);
            const int row = (i & 3) + 8*(i >> 2) + 4*half;   // 32x32 C/D row = qrow
            pw[row*36 + l31] = f2bf(p);
        }
        // same-wave LDS write->read: compiler orders via lgkmcnt, no barrier

        // P A-frags: A[m=qrow=l31][k=key]  (2x b64 each, 8B-aligned, 2-way-free banks)
        const bf16x4 a0 = *(const bf16x4*)(pr + half*8);
        const bf16x4 a1 = *(const bf16x4*)(pr + half*8 + 4);
        const bf16x4 a2 = *(const bf16x4*)(pr + 16 + half*8);
        const bf16x4 a3 = *(const bf16x4*)(pr + 16 + half*8 + 4);
        const bf16x8 pA0 = __builtin_shufflevector(a0, a1, 0, 1, 2, 3, 4, 5, 6, 7);
        const bf16x8 pA1 = __builtin_shufflevector(a2, a3, 0, 1, 2, 3, 4, 5, 6, 7);

        Cacc = __builtin_amdgcn_mfma_f32_32x32x16_bf16(pA0, vB0, Cacc, 0, 0, 0);
        Cacc = __builtin_amdgcn_mfma_f32_32x32x16_bf16(pA1, vB1, Cacc, 0, 0, 0);
    }

    // publish partials: D[m=qrow][n=d]; cols 0-15 = ctx(d), col 16 = l
    #pragma unroll
    for (int r = 0; r < 16; ++r) {
        const int row = (r & 3) + 8*(r >> 2) + 4*half;
        if (l31 < 16)        Cbuf[ks][row][h*HD + l31] = Cacc[r];
        else if (l31 == 16)  Lbuf[ks][h][row] = Cacc[r];
    }
    __syncthreads();

    // epilogue: thread = (q=tid>>4, 4 out cols); combine key-halves,
    // normalize per head, apply Wproj + bproj
    const int q   = tid >> 4;        // 0..31
    const int cbo = (tid & 15) * 4;  // 0..60
    float linv[NH];
    #pragma unroll
    for (int hh = 0; hh < NH; ++hh)
        linv[hh] = 1.0f / (Lbuf[0][hh][q] + Lbuf[1][hh][q]);

    float o0 = bproj[cbo], o1 = bproj[cbo+1], o2 = bproj[cbo+2], o3 = bproj[cbo+3];
    #pragma unroll
    for (int i = 0; i < 64; ++i) {
        const float cv = (Cbuf[0][q][i] + Cbuf[1][q][i]) * linv[i >> 4];
        const float4 wr = *(const float4*)(Wproj + i*DM + cbo);
        o0 += cv*wr.x; o1 += cv*wr.y; o2 += cv*wr.z; o3 += cv*wr.w;
    }
    float4 st; st.x = o0; st.y = o1; st.z = o2; st.w = o3;
    *(float4*)(out + ((size_t)b*TSEQ + qbase + q)*DM + cbo) = st;
}

extern "C" void kernel_launch(void* const* d_in, const int* in_sizes, int n_in,
                              void* d_out, int out_size, void* d_ws, size_t ws_size,
                              hipStream_t stream) {
    const float* x     = (const float*)d_in[0];
    const float* enc   = (const float*)d_in[1];
    const int*   mask  = (const int*)  d_in[2];
    const float* Wkv   = (const float*)d_in[3];
    const float* bkv   = (const float*)d_in[4];
    const float* Wq    = (const float*)d_in[5];
    const float* bq    = (const float*)d_in[6];
    const float* Wproj = (const float*)d_in[7];
    const float* bproj = (const float*)d_in[8];
    float* out = (float*)d_out;

    // ws: qhi,qlo,khi,klo 2MB each + vtt tiled (32 d-rows) 4MB = 12MB
    const size_t SZ = (size_t)BATCH*NH*TSEQ*HD;
    short* qhi = (short*)d_ws;
    short* qlo = qhi + SZ;
    short* khi = qlo + SZ;
    short* klo = khi + SZ;
    short* vtt = klo + SZ;   // BATCH*NH*32768 shorts

    proj_kernel<<<dim3(64, 12), dim3(256), 0, stream>>>(
        x, enc, Wkv, bkv, Wq, bq, mask, qhi, qlo, khi, klo, vtt);
    attn_kernel<<<dim3(32, 16), dim3(512), 0, stream>>>(
        qhi, qlo, khi, klo, vtt, Wproj, bproj, out);
}